// Round 1
// baseline (807.337 us; speedup 1.0000x reference)
//
#include <hip/hip_runtime.h>
#include <math.h>

#define BSZ  2
#define CDIM 256
#define NDIM 4096
#define SHIFT 110.0f

// ---------------- workspace layout (floats) ----------------
// corrT_ex: [B][C][N] (channel-major so score staging is coalesced)
static const size_t OFF_CORR_EX = 0;                         // 2*256*4096 = 2097152
static const size_t OFF_CORR_Q  = 2097152;                   // 2097152
static const size_t OFF_V_EX    = 4194304;                   // 8192
static const size_t OFF_V_Q     = 4202496;                   // 8192
static const size_t OFF_SUM_E   = 4210688;                   // 8192
static const size_t OFF_DOT_E   = 4218880;                   // 8192
static const size_t OFF_SUM_Q   = 4227072;                   // 8192
static const size_t OFF_DOT_Q   = 4235264;                   // 8192
static const size_t OFF_INV_E   = 4243456;                   // 8192
static const size_t OFF_INV_Q   = 4251648;                   // 8192
// total = 4259840 floats = ~17.04 MB

// ---------------------------------------------------------------------------
// corr kernel: corrT[b][cc][m] = sum_c feat[b][c][m] * W[cc][c]
// tile 128(m) x 128(cc), K-step 8, 8x8 microtile per thread
// grid: (N/128, C/128, 2*B)  z = sel*B + b
// ---------------------------------------------------------------------------
__global__ __launch_bounds__(256) void corr_kernel(
    const float* __restrict__ ex, const float* __restrict__ q,
    const float* __restrict__ W_ex, const float* __restrict__ W_q,
    float* __restrict__ corrT_ex, float* __restrict__ corrT_q)
{
    const int z   = blockIdx.z;
    const int sel = z >> 1;
    const int b   = z & 1;
    const float* feat = sel ? q   : ex;
    const float* W    = sel ? W_q : W_ex;
    float*       outp = sel ? corrT_q : corrT_ex;

    const int m0  = blockIdx.x * 128;
    const int cc0 = blockIdx.y * 128;
    const int t   = threadIdx.x;
    const int tx  = t & 15;       // cc microtile
    const int ty  = t >> 4;       // m microtile

    __shared__ float sA[8][128];  // feat[k][m]
    __shared__ float sB[8][128];  // W[k][cc]

    float acc[8][8];
#pragma unroll
    for (int i = 0; i < 8; i++)
#pragma unroll
        for (int j = 0; j < 8; j++) acc[i][j] = 0.f;

    for (int k0 = 0; k0 < CDIM; k0 += 8) {
        {   // sA: feat[(b*C + k0+kk)*N + m0+mi], contiguous in m
            int kk = t >> 5, mi = (t & 31) * 4;
            *(float4*)(&sA[kk][mi]) =
                *(const float4*)(feat + ((size_t)(b * CDIM + k0 + kk)) * NDIM + m0 + mi);
        }
        {   // sB: W[(cc0+ccj)*C + k0+kkb..+3] -> scatter transposed
            int ccj = t >> 1, kkb = (t & 1) * 4;
            float4 f = *(const float4*)(W + (size_t)(cc0 + ccj) * CDIM + k0 + kkb);
            sB[kkb + 0][ccj] = f.x; sB[kkb + 1][ccj] = f.y;
            sB[kkb + 2][ccj] = f.z; sB[kkb + 3][ccj] = f.w;
        }
        __syncthreads();
#pragma unroll
        for (int kk = 0; kk < 8; kk++) {
            float a[8], bb[8];
            *(float4*)(a)      = *(const float4*)(&sA[kk][ty * 8]);
            *(float4*)(a + 4)  = *(const float4*)(&sA[kk][ty * 8 + 4]);
            *(float4*)(bb)     = *(const float4*)(&sB[kk][tx * 8]);
            *(float4*)(bb + 4) = *(const float4*)(&sB[kk][tx * 8 + 4]);
#pragma unroll
            for (int i = 0; i < 8; i++)
#pragma unroll
                for (int j = 0; j < 8; j++)
                    acc[i][j] = fmaf(a[i], bb[j], acc[i][j]);
        }
        __syncthreads();
    }
    // store transposed: corrT[(b*C + cc)*N + m]
#pragma unroll
    for (int j = 0; j < 8; j++) {
        int cc = cc0 + tx * 8 + j;
        float* p = outp + ((size_t)(b * CDIM + cc)) * NDIM + m0 + ty * 8;
        float4 lo = {acc[0][j], acc[1][j], acc[2][j], acc[3][j]};
        float4 hi = {acc[4][j], acc[5][j], acc[6][j], acc[7][j]};
        *(float4*)(p)     = lo;
        *(float4*)(p + 4) = hi;
    }
}

// ---------------------------------------------------------------------------
// v kernel: v[b][n] = sum_c g[c] * feat[b][c][n]    grid (N/256, B, 2)
// ---------------------------------------------------------------------------
__global__ __launch_bounds__(256) void v_kernel(
    const float* __restrict__ ex, const float* __restrict__ q,
    const float* __restrict__ g,
    float* __restrict__ v_ex, float* __restrict__ v_q)
{
    __shared__ float sg[CDIM];
    const int t = threadIdx.x;
    sg[t] = g[t];
    __syncthreads();

    const int sel = blockIdx.z;
    const int b   = blockIdx.y;
    const float* feat = sel ? q : ex;
    float* outp       = sel ? v_q : v_ex;

    const int n = blockIdx.x * 256 + t;
    float acc = 0.f;
    for (int c = 0; c < CDIM; c++)
        acc = fmaf(sg[c], feat[((size_t)(b * CDIM + c)) * NDIM + n], acc);
    outp[b * NDIM + n] = acc;
}

// ---------------------------------------------------------------------------
// score kernel: S[m,n] = sum_k corrT[b][k][m]*key[b][k][n]
//   U = exp(S - SHIFT); write U transposed to outU[b][n][m];
//   atomically accumulate rowsum[b][m] += sum_n U, rowdot[b][m] += sum_n U*v[n]
// tile 128(m) x 128(n), K-step 8, 8x8 microtile.  grid (32, 32, B)
// ---------------------------------------------------------------------------
__global__ __launch_bounds__(256) void score_kernel(
    const float* __restrict__ corrT,   // [b][k][m]
    const float* __restrict__ key,     // [b][k][n]
    const float* __restrict__ v,       // [b][n]
    float* __restrict__ outU,          // [b][n][m]
    float* __restrict__ rowsum, float* __restrict__ rowdot)
{
    const int b  = blockIdx.z;
    const int m0 = blockIdx.x * 128;
    const int n0 = blockIdx.y * 128;
    const int t  = threadIdx.x;
    const int tx = t & 15;   // n microtile
    const int ty = t >> 4;   // m microtile

    __shared__ float sA[8][128];  // corrT[k][m]
    __shared__ float sB[8][128];  // key[k][n]

    float acc[8][8];
#pragma unroll
    for (int i = 0; i < 8; i++)
#pragma unroll
        for (int j = 0; j < 8; j++) acc[i][j] = 0.f;

    const int kk = t >> 5, xi = (t & 31) * 4;
    for (int k0 = 0; k0 < CDIM; k0 += 8) {
        *(float4*)(&sA[kk][xi]) =
            *(const float4*)(corrT + ((size_t)(b * CDIM + k0 + kk)) * NDIM + m0 + xi);
        *(float4*)(&sB[kk][xi]) =
            *(const float4*)(key + ((size_t)(b * CDIM + k0 + kk)) * NDIM + n0 + xi);
        __syncthreads();
#pragma unroll
        for (int k = 0; k < 8; k++) {
            float a[8], bb[8];
            *(float4*)(a)      = *(const float4*)(&sA[k][ty * 8]);
            *(float4*)(a + 4)  = *(const float4*)(&sA[k][ty * 8 + 4]);
            *(float4*)(bb)     = *(const float4*)(&sB[k][tx * 8]);
            *(float4*)(bb + 4) = *(const float4*)(&sB[k][tx * 8 + 4]);
#pragma unroll
            for (int i = 0; i < 8; i++)
#pragma unroll
                for (int j = 0; j < 8; j++)
                    acc[i][j] = fmaf(a[i], bb[j], acc[i][j]);
        }
        __syncthreads();
    }

    // v values for this thread's 8 n's
    float vv[8];
#pragma unroll
    for (int j = 0; j < 8; j++) vv[j] = v[b * NDIM + n0 + tx * 8 + j];

    // exp in place (global shift; no row-max pass needed, see analysis)
#pragma unroll
    for (int i = 0; i < 8; i++)
#pragma unroll
        for (int j = 0; j < 8; j++)
            acc[i][j] = __expf(acc[i][j] - SHIFT);

    // transposed store: outU[(b*N + n)*N + m]
#pragma unroll
    for (int j = 0; j < 8; j++) {
        int n = n0 + tx * 8 + j;
        float* p = outU + ((size_t)(b * NDIM + n)) * NDIM + m0 + ty * 8;
        float4 lo = {acc[0][j], acc[1][j], acc[2][j], acc[3][j]};
        float4 hi = {acc[4][j], acc[5][j], acc[6][j], acc[7][j]};
        *(float4*)(p)     = lo;
        *(float4*)(p + 4) = hi;
    }

    // per-row reductions: sum over this thread's 8 n's, then across the 16
    // tx-lanes (consecutive lanes in the wave), then one atomic per row.
#pragma unroll
    for (int i = 0; i < 8; i++) {
        float s = 0.f, dd = 0.f;
#pragma unroll
        for (int j = 0; j < 8; j++) { s += acc[i][j]; dd += acc[i][j] * vv[j]; }
#pragma unroll
        for (int off = 8; off; off >>= 1) {
            s  += __shfl_xor(s, off);
            dd += __shfl_xor(dd, off);
        }
        if (tx == 0) {
            atomicAdd(rowsum + b * NDIM + m0 + ty * 8 + i, s);
            atomicAdd(rowdot + b * NDIM + m0 + ty * 8 + i, dd);
        }
    }
}

// ---------------------------------------------------------------------------
// mask kernel: masks = sigmoid(dot/sum); also writes inv = 1/sum
// 16384 threads: idx>>13 selects {e2q, q2e}
// ---------------------------------------------------------------------------
__global__ __launch_bounds__(256) void mask_kernel(
    const float* __restrict__ sum_e, const float* __restrict__ dot_e,
    const float* __restrict__ sum_q, const float* __restrict__ dot_q,
    float* __restrict__ inv_e, float* __restrict__ inv_q,
    float* __restrict__ outp)
{
    const int idx = blockIdx.x * 256 + threadIdx.x;
    const int j = idx >> 13, i = idx & 8191;
    const float* s = j ? sum_q : sum_e;
    const float* d = j ? dot_q : dot_e;
    float* inv     = j ? inv_q : inv_e;
    const float sv = s[i];
    const float iv = 1.0f / sv;
    inv[i] = iv;
    const float x = d[i] * iv;
    outp[idx] = 1.0f / (1.0f + __expf(-x));
}

// ---------------------------------------------------------------------------
// rescale kernel: A[b][n][m] *= inv[b][m]  (m contiguous -> coalesced)
// ---------------------------------------------------------------------------
__global__ __launch_bounds__(256) void rescale_kernel(
    float* __restrict__ A, const float* __restrict__ inv)
{
    const size_t total4 = (size_t)BSZ * NDIM * NDIM / 4;
    const size_t stride = (size_t)gridDim.x * 256;
    for (size_t i4 = (size_t)blockIdx.x * 256 + threadIdx.x; i4 < total4; i4 += stride) {
        const size_t f = i4 * 4;
        const int m = (int)(f & (NDIM - 1));
        const int b = (int)(f >> 24);          // N*N = 2^24
        float4 u  = *(float4*)(A + f);
        float4 iv = *(const float4*)(inv + b * NDIM + m);
        u.x *= iv.x; u.y *= iv.y; u.z *= iv.z; u.w *= iv.w;
        *(float4*)(A + f) = u;
    }
}

// ---------------------------------------------------------------------------
extern "C" void kernel_launch(void* const* d_in, const int* in_sizes, int n_in,
                              void* d_out, int out_size, void* d_ws, size_t ws_size,
                              hipStream_t stream)
{
    const float* ex   = (const float*)d_in[0];
    const float* q    = (const float*)d_in[1];
    const float* W_ex = (const float*)d_in[2];
    const float* W_q  = (const float*)d_in[3];
    const float* g    = (const float*)d_in[4];
    float* outp = (float*)d_out;
    float* ws   = (float*)d_ws;

    float* corrT_ex = ws + OFF_CORR_EX;
    float* corrT_q  = ws + OFF_CORR_Q;
    float* v_ex     = ws + OFF_V_EX;
    float* v_q      = ws + OFF_V_Q;
    float* sum_e    = ws + OFF_SUM_E;
    float* dot_e    = ws + OFF_DOT_E;
    float* sum_q    = ws + OFF_SUM_Q;
    float* dot_q    = ws + OFF_DOT_Q;
    float* inv_e    = ws + OFF_INV_E;
    float* inv_q    = ws + OFF_INV_Q;

    float* A_e2q = outp + 16384;
    float* A_q2e = A_e2q + (size_t)BSZ * NDIM * NDIM;

    // zero the atomic accumulators (sum_e, dot_e, sum_q, dot_q are contiguous)
    hipMemsetAsync(sum_e, 0, 4 * 8192 * sizeof(float), stream);

    corr_kernel<<<dim3(NDIM / 128, CDIM / 128, 2 * BSZ), 256, 0, stream>>>(
        ex, q, W_ex, W_q, corrT_ex, corrT_q);

    v_kernel<<<dim3(NDIM / 256, BSZ, 2), 256, 0, stream>>>(ex, q, g, v_ex, v_q);

    // e2q: S = ex_corr . q ; mask uses v_ex
    score_kernel<<<dim3(32, 32, BSZ), 256, 0, stream>>>(
        corrT_ex, q, v_ex, A_e2q, sum_e, dot_e);
    // q2e: S = q_corr . ex ; mask uses v_q
    score_kernel<<<dim3(32, 32, BSZ), 256, 0, stream>>>(
        corrT_q, ex, v_q, A_q2e, sum_q, dot_q);

    mask_kernel<<<64, 256, 0, stream>>>(sum_e, dot_e, sum_q, dot_q, inv_e, inv_q, outp);

    rescale_kernel<<<32768, 256, 0, stream>>>(A_e2q, inv_e);
    rescale_kernel<<<32768, 256, 0, stream>>>(A_q2e, inv_q);
}

// Round 2
// 557.752 us; speedup vs baseline: 1.4475x; 1.4475x over previous
//
#include <hip/hip_runtime.h>
#include <math.h>

#define BSZ  2
#define CDIM 256
#define NDIM 4096
#define SHIFT 110.0f

typedef _Float16 f16;
typedef f16  f16x8 __attribute__((ext_vector_type(8)));
typedef float f32x4 __attribute__((ext_vector_type(4)));

// ---------------- memory layout ----------------
// workspace (bytes):
//   [0)          Ah_q  : 2*4096*256 f16 = 4 MB
//   [4 MB)       Al_q  : 4 MB
//   [8 MB)       Bex   : 4 MB   (ex in [b][n][c] fp16)
//   [12 MB)      floats: v_ex, v_q, sum_e, dot_e, sum_q, dot_q, inv_e, inv_q (8 x 8192)
// e2q operands (Ah_e, Al_e, Bq) are parked at the START of the A_q2e output
// region: they are consumed by score(e2q) BEFORE score(q2e) overwrites A_q2e.
static const size_t F16N   = (size_t)BSZ * NDIM * CDIM;       // 2097152 elems
static const size_t WS_FB  = 3 * F16N / 2;                    // float offset after 3 f16 arrays

__device__ __forceinline__ void gl_lds16(const void* g, void* l) {
    __builtin_amdgcn_global_load_lds(
        (const __attribute__((address_space(1))) void*)g,
        (__attribute__((address_space(3))) void*)l, 16, 0, 0);
}

// ---------------------------------------------------------------------------
// corr kernel: corr[b][m][cc] = sum_c feat[b][c][m] * W[cc][c]
// writes split fp16: Ah[b][m][cc] (hi) and Al (residual), cc contiguous.
// tile 128(m) x 128(cc), K-step 8, 8x8 microtile. grid (32, 2, 2*B)
// ---------------------------------------------------------------------------
__global__ __launch_bounds__(256) void corr_kernel(
    const float* __restrict__ ex, const float* __restrict__ q,
    const float* __restrict__ W_ex, const float* __restrict__ W_q,
    f16* __restrict__ Ah_e, f16* __restrict__ Al_e,
    f16* __restrict__ Ah_q, f16* __restrict__ Al_q)
{
    const int z   = blockIdx.z;
    const int sel = z >> 1;
    const int b   = z & 1;
    const float* feat = sel ? q   : ex;
    const float* W    = sel ? W_q : W_ex;
    f16* Ah = sel ? Ah_q : Ah_e;
    f16* Al = sel ? Al_q : Al_e;

    const int m0  = blockIdx.x * 128;
    const int cc0 = blockIdx.y * 128;
    const int t   = threadIdx.x;
    const int tx  = t & 15;       // cc microtile
    const int ty  = t >> 4;       // m microtile

    __shared__ float sA[8][128];  // feat[k][m]
    __shared__ float sB[8][128];  // W[k][cc]

    float acc[8][8];
#pragma unroll
    for (int i = 0; i < 8; i++)
#pragma unroll
        for (int j = 0; j < 8; j++) acc[i][j] = 0.f;

    for (int k0 = 0; k0 < CDIM; k0 += 8) {
        {   // sA: feat[(b*C + k0+kk)*N + m0+mi], contiguous in m
            int kk = t >> 5, mi = (t & 31) * 4;
            *(float4*)(&sA[kk][mi]) =
                *(const float4*)(feat + ((size_t)(b * CDIM + k0 + kk)) * NDIM + m0 + mi);
        }
        {   // sB: W[(cc0+ccj)*C + k0+kkb..+3] -> scatter transposed
            int ccj = t >> 1, kkb = (t & 1) * 4;
            float4 f = *(const float4*)(W + (size_t)(cc0 + ccj) * CDIM + k0 + kkb);
            sB[kkb + 0][ccj] = f.x; sB[kkb + 1][ccj] = f.y;
            sB[kkb + 2][ccj] = f.z; sB[kkb + 3][ccj] = f.w;
        }
        __syncthreads();
#pragma unroll
        for (int kk = 0; kk < 8; kk++) {
            float a[8], bb[8];
            *(float4*)(a)      = *(const float4*)(&sA[kk][ty * 8]);
            *(float4*)(a + 4)  = *(const float4*)(&sA[kk][ty * 8 + 4]);
            *(float4*)(bb)     = *(const float4*)(&sB[kk][tx * 8]);
            *(float4*)(bb + 4) = *(const float4*)(&sB[kk][tx * 8 + 4]);
#pragma unroll
            for (int i = 0; i < 8; i++)
#pragma unroll
                for (int j = 0; j < 8; j++)
                    acc[i][j] = fmaf(a[i], bb[j], acc[i][j]);
        }
        __syncthreads();
    }
    // split-fp16 store: Ah/Al[(b*N + m)*C + cc], cc contiguous (16B per row)
#pragma unroll
    for (int i = 0; i < 8; i++) {
        const int m = m0 + ty * 8 + i;
        f16x8 hv, lv;
#pragma unroll
        for (int j = 0; j < 8; j++) {
            float x = acc[i][j];
            f16 hh = (f16)x;
            hv[j] = hh;
            lv[j] = (f16)(x - (float)hh);
        }
        const size_t off = ((size_t)(b * NDIM + m)) * CDIM + cc0 + tx * 8;
        *(f16x8*)(Ah + off) = hv;
        *(f16x8*)(Al + off) = lv;
    }
}

// ---------------------------------------------------------------------------
// pack_b: Bpk[b][n][c] = fp16(feat[b][c][n])   (transpose via LDS)
// grid (64 n-tiles, 4 c-tiles, 2*B), 64x64 tile
// ---------------------------------------------------------------------------
__global__ __launch_bounds__(256) void pack_b_kernel(
    const float* __restrict__ ex, const float* __restrict__ q,
    f16* __restrict__ Bq, f16* __restrict__ Bex)
{
    const int z   = blockIdx.z;
    const int sel = z >> 1;
    const int b   = z & 1;
    const float* feat = sel ? ex : q;   // sel0: q -> Bq (e2q key), sel1: ex -> Bex
    f16* outp         = sel ? Bex : Bq;

    const int n0 = blockIdx.x * 64, c0 = blockIdx.y * 64;
    __shared__ float sT[64][65];
    const int t = threadIdx.x;
    const int tn = t & 63, tr = t >> 6;
#pragma unroll
    for (int r = 0; r < 16; ++r) {
        int c = tr + r * 4;
        sT[c][tn] = feat[((size_t)(b * CDIM + c0 + c)) * NDIM + n0 + tn];
    }
    __syncthreads();
#pragma unroll
    for (int r = 0; r < 16; ++r) {
        int n = tr + r * 4;
        outp[((size_t)(b * NDIM + n0 + n)) * CDIM + c0 + tn] = (f16)sT[tn][n];
    }
}

// ---------------------------------------------------------------------------
// v kernel: v[b][n] = sum_c g[c] * feat[b][c][n]    grid (N/256, B, 2)
// ---------------------------------------------------------------------------
__global__ __launch_bounds__(256) void v_kernel(
    const float* __restrict__ ex, const float* __restrict__ q,
    const float* __restrict__ g,
    float* __restrict__ v_ex, float* __restrict__ v_q)
{
    __shared__ float sg[CDIM];
    const int t = threadIdx.x;
    sg[t] = g[t];
    __syncthreads();

    const int sel = blockIdx.z;
    const int b   = blockIdx.y;
    const float* feat = sel ? q : ex;
    float* outp       = sel ? v_q : v_ex;

    const int n = blockIdx.x * 256 + t;
    float acc = 0.f;
    for (int c = 0; c < CDIM; c++)
        acc = fmaf(sg[c], feat[((size_t)(b * CDIM + c)) * NDIM + n], acc);
    outp[b * NDIM + n] = acc;
}

// ---------------------------------------------------------------------------
// MFMA score kernel: S[m,n] = sum_k (Ah+Al)[b][m][k] * B[b][n][k]
//   U = exp(S-SHIFT) -> outU[b][n][m]; rowsum/rowdot atomics per m.
// tile 128(m) x 128(n), 4 waves, each 2 m-frags x 8 n-frags of 16x16x32 f16.
// LDS layout fragment-native: s[kb][row][8] (16B per (kb,row) chunk).
// grid (32, 32, B)
// ---------------------------------------------------------------------------
__global__ __launch_bounds__(256) void score_mfma_kernel(
    const f16* __restrict__ Ah, const f16* __restrict__ Al,
    const f16* __restrict__ Bp, const float* __restrict__ v,
    float* __restrict__ outU,
    float* __restrict__ rowsum, float* __restrict__ rowdot)
{
    const int bb = blockIdx.z;
    const int m0 = blockIdx.x * 128;
    const int n0 = blockIdx.y * 128;
    const int t    = threadIdx.x;
    const int lane = t & 63;
    const int wv   = t >> 6;
    const int lq   = lane >> 4;   // 0..3
    const int ll   = lane & 15;

    __shared__ f16 sAh[8][128][8];   // [kb][m][8k]  16 KB
    __shared__ f16 sAl[8][128][8];
    __shared__ f16 sB [8][128][8];

    f32x4 acc[2][8];
#pragma unroll
    for (int mf = 0; mf < 2; mf++)
#pragma unroll
        for (int nf = 0; nf < 8; nf++) acc[mf][nf] = (f32x4)0.f;

    for (int k0 = 0; k0 < CDIM; k0 += 64) {
        if (k0) __syncthreads();   // protect LDS from previous iter's readers
#pragma unroll
        for (int it = 0; it < 4; ++it) {
            const int cidx = (wv * 4 + it) * 64 + lane;   // chunk = kb*128 + row
            const int kb = cidx >> 7;
            const int rr = cidx & 127;
            const size_t gA = ((size_t)(bb * NDIM + m0 + rr)) * CDIM + k0 + kb * 8;
            const size_t gB = ((size_t)(bb * NDIM + n0 + rr)) * CDIM + k0 + kb * 8;
            gl_lds16(Ah + gA, (char*)sAh + (size_t)cidx * 16);
            gl_lds16(Al + gA, (char*)sAl + (size_t)cidx * 16);
            gl_lds16(Bp + gB, (char*)sB  + (size_t)cidx * 16);
        }
        __syncthreads();
#pragma unroll
        for (int s = 0; s < 2; ++s) {          // k-step of 32 within chunk
            f16x8 bfr[8];
#pragma unroll
            for (int nf = 0; nf < 8; ++nf)
                bfr[nf] = *(const f16x8*)&sB[4 * s + lq][nf * 16 + ll][0];
#pragma unroll
            for (int mf = 0; mf < 2; ++mf) {
                f16x8 ah = *(const f16x8*)&sAh[4 * s + lq][wv * 32 + mf * 16 + ll][0];
                f16x8 al = *(const f16x8*)&sAl[4 * s + lq][wv * 32 + mf * 16 + ll][0];
#pragma unroll
                for (int nf = 0; nf < 8; ++nf) {
                    acc[mf][nf] = __builtin_amdgcn_mfma_f32_16x16x32_f16(ah, bfr[nf], acc[mf][nf], 0, 0, 0);
                    acc[mf][nf] = __builtin_amdgcn_mfma_f32_16x16x32_f16(al, bfr[nf], acc[mf][nf], 0, 0, 0);
                }
            }
        }
    }

    // ---- epilogue: exp, transposed store, row reductions ----
    float vv[8];
#pragma unroll
    for (int nf = 0; nf < 8; ++nf) vv[nf] = v[bb * NDIM + n0 + nf * 16 + ll];

    float rs[2][4], rd[2][4];
#pragma unroll
    for (int mf = 0; mf < 2; mf++)
#pragma unroll
        for (int r = 0; r < 4; r++) { rs[mf][r] = 0.f; rd[mf][r] = 0.f; }

#pragma unroll
    for (int mf = 0; mf < 2; ++mf) {
        const int mbase = m0 + wv * 32 + mf * 16 + lq * 4;   // 4 consecutive m (regs)
#pragma unroll
        for (int nf = 0; nf < 8; ++nf) {
            const int n = n0 + nf * 16 + ll;
            float4 u;
            u.x = __expf(acc[mf][nf][0] - SHIFT);
            u.y = __expf(acc[mf][nf][1] - SHIFT);
            u.z = __expf(acc[mf][nf][2] - SHIFT);
            u.w = __expf(acc[mf][nf][3] - SHIFT);
            *(float4*)(outU + ((size_t)(bb * NDIM + n)) * NDIM + mbase) = u;
            rs[mf][0] += u.x; rs[mf][1] += u.y; rs[mf][2] += u.z; rs[mf][3] += u.w;
            rd[mf][0] += u.x * vv[nf]; rd[mf][1] += u.y * vv[nf];
            rd[mf][2] += u.z * vv[nf]; rd[mf][3] += u.w * vv[nf];
        }
    }
#pragma unroll
    for (int mf = 0; mf < 2; ++mf) {
#pragma unroll
        for (int r = 0; r < 4; ++r) {
#pragma unroll
            for (int off = 1; off < 16; off <<= 1) {
                rs[mf][r] += __shfl_xor(rs[mf][r], off);
                rd[mf][r] += __shfl_xor(rd[mf][r], off);
            }
        }
        if (ll == 0) {
            const int mbase = m0 + wv * 32 + mf * 16 + lq * 4;
#pragma unroll
            for (int r = 0; r < 4; ++r) {
                atomicAdd(rowsum + bb * NDIM + mbase + r, rs[mf][r]);
                atomicAdd(rowdot + bb * NDIM + mbase + r, rd[mf][r]);
            }
        }
    }
}

// ---------------------------------------------------------------------------
// mask kernel: masks = sigmoid(dot/sum); also writes inv = 1/sum
// ---------------------------------------------------------------------------
__global__ __launch_bounds__(256) void mask_kernel(
    const float* __restrict__ sum_e, const float* __restrict__ dot_e,
    const float* __restrict__ sum_q, const float* __restrict__ dot_q,
    float* __restrict__ inv_e, float* __restrict__ inv_q,
    float* __restrict__ outp)
{
    const int idx = blockIdx.x * 256 + threadIdx.x;
    const int j = idx >> 13, i = idx & 8191;
    const float* s = j ? sum_q : sum_e;
    const float* d = j ? dot_q : dot_e;
    float* inv     = j ? inv_q : inv_e;
    const float sv = s[i];
    const float iv = 1.0f / sv;
    inv[i] = iv;
    const float x = d[i] * iv;
    outp[idx] = 1.0f / (1.0f + __expf(-x));
}

// ---------------------------------------------------------------------------
// rescale kernel: A[b][n][m] *= inv[b][m]  (m contiguous -> coalesced)
// ---------------------------------------------------------------------------
__global__ __launch_bounds__(256) void rescale_kernel(
    float* __restrict__ A, const float* __restrict__ inv)
{
    const size_t total4 = (size_t)BSZ * NDIM * NDIM / 4;
    const size_t stride = (size_t)gridDim.x * 256;
    for (size_t i4 = (size_t)blockIdx.x * 256 + threadIdx.x; i4 < total4; i4 += stride) {
        const size_t f = i4 * 4;
        const int m = (int)(f & (NDIM - 1));
        const int b = (int)(f >> 24);          // N*N = 2^24
        float4 u  = *(float4*)(A + f);
        float4 iv = *(const float4*)(inv + b * NDIM + m);
        u.x *= iv.x; u.y *= iv.y; u.z *= iv.z; u.w *= iv.w;
        *(float4*)(A + f) = u;
    }
}

// ---------------------------------------------------------------------------
extern "C" void kernel_launch(void* const* d_in, const int* in_sizes, int n_in,
                              void* d_out, int out_size, void* d_ws, size_t ws_size,
                              hipStream_t stream)
{
    const float* ex   = (const float*)d_in[0];
    const float* q    = (const float*)d_in[1];
    const float* W_ex = (const float*)d_in[2];
    const float* W_q  = (const float*)d_in[3];
    const float* g    = (const float*)d_in[4];
    float* outp = (float*)d_out;

    float* A_e2q = outp + 16384;
    float* A_q2e = A_e2q + (size_t)BSZ * NDIM * NDIM;

    // e2q operands parked in the A_q2e region (consumed before it is written)
    f16* Ah_e = (f16*)A_q2e;
    f16* Al_e = Ah_e + F16N;
    f16* Bq   = Al_e + F16N;

    // q2e operands + small arrays in workspace
    f16* Ah_q = (f16*)d_ws;
    f16* Al_q = Ah_q + F16N;
    f16* Bex  = Al_q + F16N;
    float* wsf  = (float*)d_ws + WS_FB;
    float* v_ex = wsf;
    float* v_q  = wsf + 8192;
    float* sum_e = wsf + 2 * 8192;
    float* dot_e = wsf + 3 * 8192;
    float* sum_q = wsf + 4 * 8192;
    float* dot_q = wsf + 5 * 8192;
    float* inv_e = wsf + 6 * 8192;
    float* inv_q = wsf + 7 * 8192;

    // zero the atomic accumulators (sum_e, dot_e, sum_q, dot_q contiguous)
    hipMemsetAsync(sum_e, 0, 4 * 8192 * sizeof(float), stream);

    corr_kernel<<<dim3(NDIM / 128, CDIM / 128, 2 * BSZ), 256, 0, stream>>>(
        ex, q, W_ex, W_q, Ah_e, Al_e, Ah_q, Al_q);

    pack_b_kernel<<<dim3(NDIM / 64, CDIM / 64, 2 * BSZ), 256, 0, stream>>>(
        ex, q, Bq, Bex);

    v_kernel<<<dim3(NDIM / 256, BSZ, 2), 256, 0, stream>>>(ex, q, g, v_ex, v_q);

    // e2q: S = ex_corr . q ; mask uses v_ex
    score_mfma_kernel<<<dim3(32, 32, BSZ), 256, 0, stream>>>(
        Ah_e, Al_e, Bq, v_ex, A_e2q, sum_e, dot_e);
    // q2e: S = q_corr . ex ; mask uses v_q  (overwrites the e2q operand park)
    score_mfma_kernel<<<dim3(32, 32, BSZ), 256, 0, stream>>>(
        Ah_q, Al_q, Bex, v_q, A_q2e, sum_q, dot_q);

    mask_kernel<<<64, 256, 0, stream>>>(sum_e, dot_e, sum_q, dot_q, inv_e, inv_q, outp);

    rescale_kernel<<<32768, 256, 0, stream>>>(A_e2q, inv_e);
    rescale_kernel<<<32768, 256, 0, stream>>>(A_q2e, inv_q);
}